// Round 16
// baseline (152.836 us; speedup 1.0000x reference)
//
#include <hip/hip_runtime.h>
#include <stdint.h>

#define NBOX 4096
#define IMG 640.0f

typedef unsigned long long u64;
typedef unsigned int u32;

// ws layout (bytes):
//   [0      .. 16384)    sx1   (4096 f32, sorted)
//   [16384  .. 32768)    sy1
//   [32768  .. 49152)    sx2
//   [49152  .. 65536)    sy2
//   [65536  .. 81920)    sconf
//   [81920  .. 81924)    M (int)
//   [86016  .. 118784)   diagR  (4096 u64): row r's suppression word blk(r)
//   [118784 .. 151552)   carry1 (4096 u64): row r's suppression word blk(r)+1
//   [196608 .. 2293760)  mask (ROW-major: mask[row][word], 4096 x 64 u64 = 2 MB)
//   [2293760 .. 2555904) rank_partial (16 x 4096 int = 256 KB)

__global__ __launch_bounds__(256) void k_rank(const float* __restrict__ raw,
                                              int* __restrict__ rank_partial, int* __restrict__ Mp) {
    const int bi = blockIdx.x, bj = blockIdx.y;
    const int t = threadIdx.x;
    const int i = bi * 256 + t;
    if (bi == 0 && bj == 0 && t == 0) *Mp = 0;
    __shared__ float cj[256];
    cj[t] = raw[(bj * 256 + t) * 5 + 4];
    __syncthreads();

    const float ci = raw[i * 5 + 4];
    const int jbase = bj * 256;
    int rank = 0;
    const float4* c4 = reinterpret_cast<const float4*>(cj);
#pragma unroll 4
    for (int j4 = 0; j4 < 64; ++j4) {
        float4 c = c4[j4];
        int j = jbase + j4 * 4;
        rank += (c.x > ci || (c.x == ci && (j + 0) < i)) ? 1 : 0;
        rank += (c.y > ci || (c.y == ci && (j + 1) < i)) ? 1 : 0;
        rank += (c.z > ci || (c.z == ci && (j + 2) < i)) ? 1 : 0;
        rank += (c.w > ci || (c.w == ci && (j + 3) < i)) ? 1 : 0;
    }
    rank_partial[bj * NBOX + i] = rank;
}

__global__ __launch_bounds__(256) void k_scatter(const float* __restrict__ raw,
                                                 const int* __restrict__ rank_partial,
                                                 float* __restrict__ sx1, float* __restrict__ sy1,
                                                 float* __restrict__ sx2, float* __restrict__ sy2,
                                                 float* __restrict__ sconf, int* __restrict__ Mp) {
    const int i = blockIdx.x * 256 + threadIdx.x;
    const float ci = raw[i * 5 + 4];
    const bool vi = (ci >= 0.5f);

    int rank = 0;
#pragma unroll
    for (int k = 0; k < 16; ++k) rank += rank_partial[k * NBOX + i];

    u64 bal = __ballot(vi);
    if ((threadIdx.x & 63) == 0) atomicAdd(Mp, (int)__popcll(bal));

    if (vi) {
        // Strict IEEE ops (no FMA contraction) to match the numpy-evaluated reference.
        float cx = __fmul_rn(raw[i * 5 + 0], IMG);
        float cy = __fmul_rn(raw[i * 5 + 1], IMG);
        float w  = __fmul_rn(raw[i * 5 + 2], IMG);
        float h  = __fmul_rn(raw[i * 5 + 3], IMG);
        float hw = __fmul_rn(w, 0.5f);
        float hh = __fmul_rn(h, 0.5f);
        sx1[rank]   = __fsub_rn(cx, hw);
        sy1[rank]   = __fsub_rn(cy, hh);
        sx2[rank]   = __fadd_rn(cx, hw);
        sy2[rank]   = __fadd_rn(cy, hh);
        sconf[rank] = ci;
    }
}

// Block (bx, w): rows r = bx*256+tid, word w. ROW-major mask (rows contiguous,
// for the scan's coalesced kept-row broadcast loads); also extracts diag word
// + carry1 column as contiguous streams.
__global__ __launch_bounds__(256) void k_mask(const float* __restrict__ sx1, const float* __restrict__ sy1,
                                              const float* __restrict__ sx2, const float* __restrict__ sy2,
                                              const int* __restrict__ Mp,
                                              u64* __restrict__ mask, u64* __restrict__ diagR,
                                              u64* __restrict__ carry1) {
    const int w = blockIdx.y;
    const int r = blockIdx.x * 256 + threadIdx.x;
    const int t = threadIdx.x;
    const int M = *Mp;

    __shared__ float cx1[64], cy1[64], cx2[64], cy2[64], car[64];
    if (t < 64) {
        int j = (w << 6) + t;
        float a1 = sx1[j], b1 = sy1[j], a2 = sx2[j], b2 = sy2[j];
        cx1[t] = a1; cy1[t] = b1; cx2[t] = a2; cy2[t] = b2;
        car[t] = __fmul_rn(__fsub_rn(a2, a1), __fsub_rn(b2, b1));
    }
    __syncthreads();

    u64 bits = 0ULL;
    if (r < M) {
        const float x1 = sx1[r], y1 = sy1[r], x2 = sx2[r], y2 = sy2[r];
        const float area_i = __fmul_rn(__fsub_rn(x2, x1), __fsub_rn(y2, y1));
        const int bmax = min(64, M - (w << 6));       // j < M
        const int bmin = max(0, r + 1 - (w << 6));    // j > r
        for (int b = bmin; b < bmax; ++b) {
            float xx1 = fmaxf(x1, cx1[b]);
            float yy1 = fmaxf(y1, cy1[b]);
            float xx2 = fminf(x2, cx2[b]);
            float yy2 = fminf(y2, cy2[b]);
            float iw = fmaxf(__fsub_rn(xx2, xx1), 0.0f);
            float ih = fmaxf(__fsub_rn(yy2, yy1), 0.0f);
            float inter = __fmul_rn(iw, ih);
            float uni = __fsub_rn(__fadd_rn(area_i, car[b]), inter);
            float iou = __fdiv_rn(inter, fmaxf(uni, 1e-9f));
            if (iou > 0.5f) bits |= (1ULL << b);
        }
        mask[((size_t)r << 6) + w] = bits;            // row-major
    }

    const int rblk = r >> 6;
    if (rblk == w)     diagR[r]  = bits;
    if (rblk + 1 == w) carry1[r] = bits;
}

// SINGLE-WAVE greedy scan, no barriers, all state in registers:
//  - diagR/carry1: 6-phase named stream ring (issued 6 blocks ahead, no copies)
//  - kept-row fold: lag-2 via 2x16 NAMED u64 scalars (arrays get demoted to
//    scratch -- R12/R13 lesson); issued at block b, folded at b+2.
//    Unused slots duplicate the first kept row (idempotent OR); kb==0 skips.
//  - carry: block b-1 -> word b accumulated in-resolve from carry1 stream.
// NOTE: __builtin_amdgcn_readlane returns *int* -- truncate to u32 before
// widening ((u64)(int) sign-extends: R6/R10 bug).
__global__ __launch_bounds__(256) void k_scan(const int* __restrict__ Mp,
                                              const u64* __restrict__ mask,
                                              const u64* __restrict__ diagR,
                                              const u64* __restrict__ carry1,
                                              const float* __restrict__ sx1, const float* __restrict__ sy1,
                                              const float* __restrict__ sx2, const float* __restrict__ sy2,
                                              const float* __restrict__ sconf,
                                              float* __restrict__ out) {
    __shared__ u64 kbArr[64];
    const int tid = threadIdx.x;
    const int lane = tid & 63;
    const int M = *Mp;
    const int nblk = (M + 63) >> 6;

    if (tid < 64) kbArr[tid] = 0ULL;

    if ((tid >> 6) == 0 && nblk > 0) {
        __builtin_amdgcn_s_setprio(1);

        // 6-phase streams
        u64 d0 = 0, d1 = 0, d2 = 0, d3 = 0, d4 = 0, d5 = 0;
        u64 e0 = 0, e1 = 0, e2 = 0, e3 = 0, e4 = 0, e5 = 0;
        d0 = diagR[lane];                 e0 = carry1[lane];
        if (1 < nblk) { d1 = diagR[(1 << 6) + lane]; e1 = carry1[(1 << 6) + lane]; }
        if (2 < nblk) { d2 = diagR[(2 << 6) + lane]; e2 = carry1[(2 << 6) + lane]; }
        if (3 < nblk) { d3 = diagR[(3 << 6) + lane]; e3 = carry1[(3 << 6) + lane]; }
        if (4 < nblk) { d4 = diagR[(4 << 6) + lane]; e4 = carry1[(4 << 6) + lane]; }
        if (5 < nblk) { d5 = diagR[(5 << 6) + lane]; e5 = carry1[(5 << 6) + lane]; }

        // 2-phase lag fold buffers: NAMED scalars (never arrays)
        u64 fA0=0,fA1=0,fA2=0,fA3=0,fA4=0,fA5=0,fA6=0,fA7=0,
            fA8=0,fA9=0,fA10=0,fA11=0,fA12=0,fA13=0,fA14=0,fA15=0;
        u64 fB0=0,fB1=0,fB2=0,fB3=0,fB4=0,fB5=0,fB6=0,fB7=0,
            fB8=0,fB9=0,fB10=0,fB11=0,fB12=0,fB13=0,fB14=0,fB15=0;
        int cntA = 0, cntB = 0;
        u64 ofA = 0ULL, ofB = 0ULL;

        u32 rvlo = 0, rvhi = 0;          // lane-distributed remv word `lane`
        u64 carry = 0ULL;                // block b-1 kept -> word b

#define FOLD16(P, BF)                                                         \
    do {                                                                      \
        if (cnt##P) {                                                         \
            u64 facc = f##P##0 | f##P##1 | f##P##2 | f##P##3                  \
                     | f##P##4 | f##P##5 | f##P##6 | f##P##7                  \
                     | f##P##8 | f##P##9 | f##P##10 | f##P##11                \
                     | f##P##12 | f##P##13 | f##P##14 | f##P##15;             \
            if (__builtin_expect(of##P != 0ULL, 0)) {                         \
                u64 tt_ = of##P;                                              \
                const u64* rb2_ = mask + ((size_t)(((BF) - 2) << 6) << 6);    \
                while (tt_) { int ii_ = __builtin_ctzll(tt_); tt_ &= tt_ - 1; \
                              facc |= rb2_[((size_t)ii_ << 6) + lane]; }      \
            }                                                                 \
            rvlo |= (u32)facc; rvhi |= (u32)(facc >> 32);                     \
        }                                                                     \
    } while (0)

#define ISLOT(NAME)                                                           \
    do {                                                                      \
        const int ik_ = tt_ ? __builtin_ctzll(tt_) : i0_;                     \
        if (tt_) tt_ &= tt_ - 1;                                              \
        NAME = rowb_[((size_t)ik_ << 6) + lane];                              \
    } while (0)

#define ISSUE16(P, BI)                                                        \
    do {                                                                      \
        u64 tt_ = kb;                                                         \
        const int i0_ = kb ? __builtin_ctzll(kb) : 0;                         \
        const u64* rowb_ = mask + ((size_t)((BI) << 6) << 6);                 \
        ISLOT(f##P##0);  ISLOT(f##P##1);  ISLOT(f##P##2);  ISLOT(f##P##3);    \
        ISLOT(f##P##4);  ISLOT(f##P##5);  ISLOT(f##P##6);  ISLOT(f##P##7);    \
        ISLOT(f##P##8);  ISLOT(f##P##9);  ISLOT(f##P##10); ISLOT(f##P##11);   \
        ISLOT(f##P##12); ISLOT(f##P##13); ISLOT(f##P##14); ISLOT(f##P##15);   \
        cnt##P = (kb != 0ULL) ? 1 : 0;                                        \
        of##P = tt_;                                                          \
    } while (0)

#define STEP(B, DD, EE, P)                                                    \
    do {                                                                      \
        const int b_ = (B);                                                   \
        if (b_ < nblk) {                                                      \
            FOLD16(P, b_);                   /* block b_-2 lands in rv */     \
            u32 rbl = (u32)__builtin_amdgcn_readlane(rvlo, b_);               \
            u32 rbh = (u32)__builtin_amdgcn_readlane(rvhi, b_);               \
            const u64 rb = (((u64)rbh << 32) | (u64)rbl) | carry;             \
            const int rem = M - (b_ << 6);                                    \
            const u64 valid = (rem >= 64) ? ~0ULL : ((1ULL << rem) - 1ULL);   \
            u64 alive = valid & ~rb;                                          \
            u64 kb = 0ULL, car = 0ULL;                                        \
            const u32 dlo = (u32)(DD), dhi = (u32)((DD) >> 32);               \
            const u32 el = (u32)(EE), eh = (u32)((EE) >> 32);                 \
            while (alive) {                                                   \
                int i = __builtin_ctzll(alive); alive &= alive - 1;           \
                kb |= (1ULL << i);                                            \
                u32 lo = (u32)__builtin_amdgcn_readlane(dlo, i);              \
                u32 hi = (u32)__builtin_amdgcn_readlane(dhi, i);              \
                u32 p  = (u32)__builtin_amdgcn_readlane(el, i);               \
                u32 q  = (u32)__builtin_amdgcn_readlane(eh, i);               \
                alive &= ~(((u64)hi << 32) | (u64)lo);   /* on-chain */       \
                car |= ((u64)q << 32) | (u64)p;          /* off-chain */      \
            }                                                                 \
            carry = car;                                                      \
            if (lane == 0) kbArr[b_] = kb;                                    \
            ISSUE16(P, b_);                  /* folds at b_+2 */              \
            if (b_ + 6 < nblk) {                                              \
                (DD) = diagR [((b_ + 6) << 6) + lane];                        \
                (EE) = carry1[((b_ + 6) << 6) + lane];                        \
            }                                                                 \
        }                                                                     \
    } while (0)

        for (int base = 0; base < nblk; base += 6) {
            STEP(base + 0, d0, e0, A);
            STEP(base + 1, d1, e1, B);
            STEP(base + 2, d2, e2, A);
            STEP(base + 3, d3, e3, B);
            STEP(base + 4, d4, e4, A);
            STEP(base + 5, d5, e5, B);
        }
#undef STEP
#undef ISSUE16
#undef ISLOT
#undef FOLD16
    }
    __syncthreads();

    // ---- fused output epilogue ----
    for (int g = tid; g < NBOX * 5; g += 256) {
        const int r = g / 5;
        const int c = g - r * 5;
        bool kept = false;
        if (r < M) kept = ((kbArr[r >> 6] >> (r & 63)) & 1ULL) != 0ULL;
        float vv = 0.0f;
        if (kept) {
            const float* arr = (c == 0) ? sx1 : (c == 1) ? sy1 : (c == 2) ? sx2 : (c == 3) ? sy2 : sconf;
            vv = arr[r];
        }
        out[g] = vv;
    }
}

extern "C" void kernel_launch(void* const* d_in, const int* in_sizes, int n_in,
                              void* d_out, int out_size, void* d_ws, size_t ws_size,
                              hipStream_t stream) {
    const float* raw = (const float*)d_in[0];
    char* ws = (char*)d_ws;
    float* sx1 = (float*)(ws + 0);
    float* sy1 = (float*)(ws + 16384);
    float* sx2 = (float*)(ws + 32768);
    float* sy2 = (float*)(ws + 49152);
    float* sconf = (float*)(ws + 65536);
    int* Mp = (int*)(ws + 81920);
    u64* diagR  = (u64*)(ws + 86016);
    u64* carry1 = (u64*)(ws + 118784);
    u64* mask = (u64*)(ws + 196608);
    int* rank_partial = (int*)(ws + 2293760);
    float* out = (float*)d_out;

    k_rank<<<dim3(16, 16), dim3(256), 0, stream>>>(raw, rank_partial, Mp);
    k_scatter<<<dim3(16), dim3(256), 0, stream>>>(raw, rank_partial, sx1, sy1, sx2, sy2, sconf, Mp);
    k_mask<<<dim3(16, 64), dim3(256), 0, stream>>>(sx1, sy1, sx2, sy2, Mp, mask, diagR, carry1);
    k_scan<<<dim3(1), dim3(256), 0, stream>>>(Mp, mask, diagR, carry1, sx1, sy1, sx2, sy2, sconf, out);
}

// Round 17
// 94.670 us; speedup vs baseline: 1.6144x; 1.6144x over previous
//
#include <hip/hip_runtime.h>
#include <stdint.h>

#define NBOX 4096
#define IMG 640.0f

typedef unsigned long long u64;
typedef unsigned int u32;

// ws layout (bytes):
//   [0      .. 16384)    sx1   (4096 f32, sorted)
//   [16384  .. 32768)    sy1
//   [32768  .. 49152)    sx2
//   [49152  .. 65536)    sy2
//   [65536  .. 81920)    sconf
//   [81920  .. 81924)    M (int)
//   [86016  .. 118784)   diagR  (4096 u64): row r's word blk(r)
//   [118784 .. 151552)   carry1 (4096 u64): row r's word blk(r)+1
//   [151552 .. 184320)   carry2 (4096 u64): row r's word blk(r)+2
//   [184320 .. 217088)   carry3 (4096 u64): row r's word blk(r)+3
//   [262144 .. 2359296)  maskT (COLUMN-major: maskT[word][row], 64 x 4096 u64 = 2 MB)
//   [2359296 .. 2621440) rank_partial (16 x 4096 int = 256 KB)

__global__ __launch_bounds__(256) void k_rank(const float* __restrict__ raw,
                                              int* __restrict__ rank_partial, int* __restrict__ Mp) {
    const int bi = blockIdx.x, bj = blockIdx.y;
    const int t = threadIdx.x;
    const int i = bi * 256 + t;
    if (bi == 0 && bj == 0 && t == 0) *Mp = 0;
    __shared__ float cj[256];
    cj[t] = raw[(bj * 256 + t) * 5 + 4];
    __syncthreads();

    const float ci = raw[i * 5 + 4];
    const int jbase = bj * 256;
    int rank = 0;
    const float4* c4 = reinterpret_cast<const float4*>(cj);
#pragma unroll 4
    for (int j4 = 0; j4 < 64; ++j4) {
        float4 c = c4[j4];
        int j = jbase + j4 * 4;
        rank += (c.x > ci || (c.x == ci && (j + 0) < i)) ? 1 : 0;
        rank += (c.y > ci || (c.y == ci && (j + 1) < i)) ? 1 : 0;
        rank += (c.z > ci || (c.z == ci && (j + 2) < i)) ? 1 : 0;
        rank += (c.w > ci || (c.w == ci && (j + 3) < i)) ? 1 : 0;
    }
    rank_partial[bj * NBOX + i] = rank;
}

__global__ __launch_bounds__(256) void k_scatter(const float* __restrict__ raw,
                                                 const int* __restrict__ rank_partial,
                                                 float* __restrict__ sx1, float* __restrict__ sy1,
                                                 float* __restrict__ sx2, float* __restrict__ sy2,
                                                 float* __restrict__ sconf, int* __restrict__ Mp) {
    const int i = blockIdx.x * 256 + threadIdx.x;
    const float ci = raw[i * 5 + 4];
    const bool vi = (ci >= 0.5f);

    int rank = 0;
#pragma unroll
    for (int k = 0; k < 16; ++k) rank += rank_partial[k * NBOX + i];

    u64 bal = __ballot(vi);
    if ((threadIdx.x & 63) == 0) atomicAdd(Mp, (int)__popcll(bal));

    if (vi) {
        // Strict IEEE ops (no FMA contraction) to match the numpy-evaluated reference.
        float cx = __fmul_rn(raw[i * 5 + 0], IMG);
        float cy = __fmul_rn(raw[i * 5 + 1], IMG);
        float w  = __fmul_rn(raw[i * 5 + 2], IMG);
        float h  = __fmul_rn(raw[i * 5 + 3], IMG);
        float hw = __fmul_rn(w, 0.5f);
        float hh = __fmul_rn(h, 0.5f);
        sx1[rank]   = __fsub_rn(cx, hw);
        sy1[rank]   = __fsub_rn(cy, hh);
        sx2[rank]   = __fadd_rn(cx, hw);
        sy2[rank]   = __fadd_rn(cy, hh);
        sconf[rank] = ci;
    }
}

// Block (bx, w): rows r = bx*256+tid, word w. Column-major store (coalesced);
// extracts diag word + carry1/2/3 columns as contiguous streams.
__global__ __launch_bounds__(256) void k_mask(const float* __restrict__ sx1, const float* __restrict__ sy1,
                                              const float* __restrict__ sx2, const float* __restrict__ sy2,
                                              const int* __restrict__ Mp,
                                              u64* __restrict__ maskT, u64* __restrict__ diagR,
                                              u64* __restrict__ carry1, u64* __restrict__ carry2,
                                              u64* __restrict__ carry3) {
    const int w = blockIdx.y;
    const int r = blockIdx.x * 256 + threadIdx.x;
    const int t = threadIdx.x;
    const int M = *Mp;

    __shared__ float cx1[64], cy1[64], cx2[64], cy2[64], car[64];
    if (t < 64) {
        int j = (w << 6) + t;
        float a1 = sx1[j], b1 = sy1[j], a2 = sx2[j], b2 = sy2[j];
        cx1[t] = a1; cy1[t] = b1; cx2[t] = a2; cy2[t] = b2;
        car[t] = __fmul_rn(__fsub_rn(a2, a1), __fsub_rn(b2, b1));
    }
    __syncthreads();

    u64 bits = 0ULL;
    if (r < M) {
        const float x1 = sx1[r], y1 = sy1[r], x2 = sx2[r], y2 = sy2[r];
        const float area_i = __fmul_rn(__fsub_rn(x2, x1), __fsub_rn(y2, y1));
        const int bmax = min(64, M - (w << 6));       // j < M
        const int bmin = max(0, r + 1 - (w << 6));    // j > r
        for (int b = bmin; b < bmax; ++b) {
            float xx1 = fmaxf(x1, cx1[b]);
            float yy1 = fmaxf(y1, cy1[b]);
            float xx2 = fminf(x2, cx2[b]);
            float yy2 = fminf(y2, cy2[b]);
            float iw = fmaxf(__fsub_rn(xx2, xx1), 0.0f);
            float ih = fmaxf(__fsub_rn(yy2, yy1), 0.0f);
            float inter = __fmul_rn(iw, ih);
            float uni = __fsub_rn(__fadd_rn(area_i, car[b]), inter);
            float iou = __fdiv_rn(inter, fmaxf(uni, 1e-9f));
            if (iou > 0.5f) bits |= (1ULL << b);
        }
        maskT[((size_t)w << 12) + r] = bits;          // coalesced column-major
    }

    const int rblk = r >> 6;
    if (rblk == w)     diagR[r]  = bits;
    if (rblk + 1 == w) carry1[r] = bits;
    if (rblk + 2 == w) carry2[r] = bits;
    if (rblk + 3 == w) carry3[r] = bits;
}

// 9 waves, 1 KiB LDS, SUPER-BLOCKS of 128 boxes -> HALF the barriers (16).
//  wave 0 : resolve blocks 2s then 2s+1 back-to-back in registers; carries
//           x1/x2/x3 (B0->words +1,+2,+3) and y1/y2 (B1->+1,+2) accumulated
//           off-chain; streams ping-pong 1 super ahead (7 contiguous loads).
//  waves 1-8: fold super s-1 (blocks 2s-2,2s-1) into remvArr[2s+2..63] from
//           ping-pong register buffers loaded 1 super ahead (coalesced).
// NOTE: __builtin_amdgcn_readlane returns *int* -- truncate to u32 before
// widening ((u64)(int) sign-extends: R6/R10 bug).
__global__ __launch_bounds__(576) void k_scan(const int* __restrict__ Mp,
                                              const u64* __restrict__ maskT,
                                              const u64* __restrict__ diagR,
                                              const u64* __restrict__ carry1,
                                              const u64* __restrict__ carry2,
                                              const u64* __restrict__ carry3,
                                              const float* __restrict__ sx1, const float* __restrict__ sy1,
                                              const float* __restrict__ sx2, const float* __restrict__ sy2,
                                              const float* __restrict__ sconf,
                                              float* __restrict__ out) {
    __shared__ u64 remvArr[64];
    __shared__ u64 kbArr[64];
    const int tid = threadIdx.x;
    const int wave = tid >> 6;
    const int lane = tid & 63;
    const int M = *Mp;
    const int nblk = (M + 63) >> 6;
    const int nsup = (nblk + 1) >> 1;

    if (tid < 64) { remvArr[tid] = 0ULL; kbArr[tid] = 0ULL; }
    __syncthreads();

    if (wave == 0) {
        __builtin_amdgcn_s_setprio(1);
        u64 dP0 = diagR[lane], cP01 = carry1[lane], cP02 = carry2[lane], cP03 = carry3[lane];
        u64 dP1 = 0, cP12 = 0, cP13 = 0;
        if (1 < nblk) { dP1 = diagR[64 + lane]; cP12 = carry1[64 + lane]; cP13 = carry2[64 + lane]; }
        u64 dQ0 = 0, dQ1 = 0, cQ01 = 0, cQ02 = 0, cQ03 = 0, cQ12 = 0, cQ13 = 0;
        u64 cw0 = 0ULL, cw1 = 0ULL;   // super s-1 -> words 2s, 2s+1

#define WSUPER(S, D0, D1, C01, C02, C03, C12, C13, ND0, ND1, NC01, NC02, NC03, NC12, NC13) \
    do {                                                                      \
        const int s_ = (S);                                                   \
        if (s_ < nsup) {                                                      \
            const int B0_ = s_ << 1;                                          \
            const int B1_ = B0_ + 1;                                          \
            u64 kb0_ = 0ULL, x1_ = 0ULL, x2_ = 0ULL, x3_ = 0ULL;              \
            {                                                                 \
                const u64 rb_ = remvArr[B0_] | cw0;                           \
                const int rem_ = M - (B0_ << 6);                              \
                const u64 valid_ = (rem_ >= 64) ? ~0ULL : ((1ULL << rem_) - 1ULL); \
                u64 alive_ = valid_ & ~rb_;                                   \
                const u32 dlo_ = (u32)(D0), dhi_ = (u32)((D0) >> 32);         \
                const u32 e1l_ = (u32)(C01), e1h_ = (u32)((C01) >> 32);       \
                const u32 e2l_ = (u32)(C02), e2h_ = (u32)((C02) >> 32);       \
                const u32 e3l_ = (u32)(C03), e3h_ = (u32)((C03) >> 32);       \
                while (alive_) {                                              \
                    int i_ = __builtin_ctzll(alive_); alive_ &= alive_ - 1;   \
                    kb0_ |= (1ULL << i_);                                     \
                    u32 lo_ = (u32)__builtin_amdgcn_readlane(dlo_, i_);       \
                    u32 hi_ = (u32)__builtin_amdgcn_readlane(dhi_, i_);       \
                    u32 p1_ = (u32)__builtin_amdgcn_readlane(e1l_, i_);       \
                    u32 q1_ = (u32)__builtin_amdgcn_readlane(e1h_, i_);       \
                    u32 p2_ = (u32)__builtin_amdgcn_readlane(e2l_, i_);       \
                    u32 q2_ = (u32)__builtin_amdgcn_readlane(e2h_, i_);       \
                    u32 p3_ = (u32)__builtin_amdgcn_readlane(e3l_, i_);       \
                    u32 q3_ = (u32)__builtin_amdgcn_readlane(e3h_, i_);       \
                    alive_ &= ~(((u64)hi_ << 32) | (u64)lo_);   /* on-chain */ \
                    x1_ |= ((u64)q1_ << 32) | (u64)p1_;                       \
                    x2_ |= ((u64)q2_ << 32) | (u64)p2_;                       \
                    x3_ |= ((u64)q3_ << 32) | (u64)p3_;                       \
                }                                                             \
                if (lane == 0) kbArr[B0_] = kb0_;                             \
            }                                                                 \
            u64 y1_ = 0ULL, y2_ = 0ULL;                                       \
            if (B1_ < nblk) {                                                 \
                u64 kb1_ = 0ULL;                                              \
                const u64 rb_ = remvArr[B1_] | cw1 | x1_;                     \
                const int rem_ = M - (B1_ << 6);                              \
                const u64 valid_ = (rem_ >= 64) ? ~0ULL : ((1ULL << rem_) - 1ULL); \
                u64 alive_ = valid_ & ~rb_;                                   \
                const u32 dlo_ = (u32)(D1), dhi_ = (u32)((D1) >> 32);         \
                const u32 e1l_ = (u32)(C12), e1h_ = (u32)((C12) >> 32);       \
                const u32 e2l_ = (u32)(C13), e2h_ = (u32)((C13) >> 32);       \
                while (alive_) {                                              \
                    int i_ = __builtin_ctzll(alive_); alive_ &= alive_ - 1;   \
                    kb1_ |= (1ULL << i_);                                     \
                    u32 lo_ = (u32)__builtin_amdgcn_readlane(dlo_, i_);       \
                    u32 hi_ = (u32)__builtin_amdgcn_readlane(dhi_, i_);       \
                    u32 p1_ = (u32)__builtin_amdgcn_readlane(e1l_, i_);       \
                    u32 q1_ = (u32)__builtin_amdgcn_readlane(e1h_, i_);       \
                    u32 p2_ = (u32)__builtin_amdgcn_readlane(e2l_, i_);       \
                    u32 q2_ = (u32)__builtin_amdgcn_readlane(e2h_, i_);       \
                    alive_ &= ~(((u64)hi_ << 32) | (u64)lo_);                 \
                    y1_ |= ((u64)q1_ << 32) | (u64)p1_;                       \
                    y2_ |= ((u64)q2_ << 32) | (u64)p2_;                       \
                }                                                             \
                if (lane == 0) kbArr[B1_] = kb1_;                             \
            }                                                                 \
            cw0 = x2_ | y1_;                                                  \
            cw1 = x3_ | y2_;                                                  \
            if (s_ + 1 < nsup) {                                              \
                const int nB0_ = (s_ + 1) << 1, nB1_ = nB0_ + 1;              \
                (ND0)  = diagR [(nB0_ << 6) + lane];                          \
                (NC01) = carry1[(nB0_ << 6) + lane];                          \
                (NC02) = carry2[(nB0_ << 6) + lane];                          \
                (NC03) = carry3[(nB0_ << 6) + lane];                          \
                (ND1)  = diagR [(nB1_ << 6) + lane];                          \
                (NC12) = carry1[(nB1_ << 6) + lane];                          \
                (NC13) = carry2[(nB1_ << 6) + lane];                          \
            }                                                                 \
            asm volatile("s_waitcnt lgkmcnt(0)" ::: "memory");                \
            __builtin_amdgcn_s_barrier();                                     \
            __builtin_amdgcn_sched_barrier(0);                                \
        }                                                                     \
    } while (0)

        for (int ss = 0; ss < nsup; ss += 2) {
            WSUPER(ss,     dP0, dP1, cP01, cP02, cP03, cP12, cP13,
                           dQ0, dQ1, cQ01, cQ02, cQ03, cQ12, cQ13);
            WSUPER(ss + 1, dQ0, dQ1, cQ01, cQ02, cQ03, cQ12, cQ13,
                           dP0, dP1, cP01, cP02, cP03, cP12, cP13);
        }
#undef WSUPER
    } else {
        const int w1 = wave - 1;            // 0..7
        const int chunk = tid & 7;          // row class (rows chunk + 8k)
        const int slot = (tid >> 3) & 7;    // word slot
        const int idx = (w1 << 3) + slot;   // 0..63
        u64 vX[8], vY[8];                   // rows of blocks 2s, 2s+1 (static idx)

#define BSUPER(S)                                                             \
    do {                                                                      \
        const int s_ = (S);                                                   \
        if (s_ < nsup) {                                                      \
            if (s_ >= 1) {                                                    \
                const u64 kb0_ = kbArr[(s_ << 1) - 2];                        \
                const u64 kb1_ = kbArr[(s_ << 1) - 1];                        \
                const int W_ = (s_ << 1) + 2 + idx;                           \
                if (W_ < 64 && (kb0_ | kb1_) != 0ULL) {                       \
                    u64 acc_ = 0ULL;                                          \
                    _Pragma("unroll")                                         \
                    for (int k = 0; k < 8; ++k) {                             \
                        const int r_ = chunk + (k << 3);                      \
                        acc_ |= (((kb0_ >> r_) & 1ULL) ? vX[k] : 0ULL);       \
                        acc_ |= (((kb1_ >> r_) & 1ULL) ? vY[k] : 0ULL);       \
                    }                                                         \
                    acc_ |= __shfl_xor(acc_, 1);                              \
                    acc_ |= __shfl_xor(acc_, 2);                              \
                    acc_ |= __shfl_xor(acc_, 4);                              \
                    if (chunk == 0) remvArr[W_] |= acc_;                      \
                }                                                             \
            }                                                                 \
            if (s_ + 1 < nsup) {                                              \
                const int Wn_ = (s_ << 1) + 4 + idx;                          \
                const int Wc_ = (Wn_ < 64) ? Wn_ : 63;                        \
                const u64* cbX_ = maskT + ((size_t)Wc_ << 12) + ((size_t)(s_ << 1) << 6); \
                const u64* cbY_ = cbX_ + 64;                                  \
                _Pragma("unroll")                                             \
                for (int k = 0; k < 8; ++k) {                                 \
                    vX[k] = cbX_[chunk + (k << 3)];                           \
                    vY[k] = cbY_[chunk + (k << 3)];                           \
                }                                                             \
            }                                                                 \
            asm volatile("s_waitcnt lgkmcnt(0)" ::: "memory");                \
            __builtin_amdgcn_s_barrier();                                     \
            __builtin_amdgcn_sched_barrier(0);                                \
        }                                                                     \
    } while (0)

        for (int ss = 0; ss < nsup; ss += 2) {
            BSUPER(ss);
            BSUPER(ss + 1);
        }
#undef BSUPER
    }
    __syncthreads();

    // ---- fused output epilogue ----
    for (int g = tid; g < NBOX * 5; g += 576) {
        const int r = g / 5;
        const int c = g - r * 5;
        bool kept = false;
        if (r < M) kept = ((kbArr[r >> 6] >> (r & 63)) & 1ULL) != 0ULL;
        float vv = 0.0f;
        if (kept) {
            const float* arr = (c == 0) ? sx1 : (c == 1) ? sy1 : (c == 2) ? sx2 : (c == 3) ? sy2 : sconf;
            vv = arr[r];
        }
        out[g] = vv;
    }
}

extern "C" void kernel_launch(void* const* d_in, const int* in_sizes, int n_in,
                              void* d_out, int out_size, void* d_ws, size_t ws_size,
                              hipStream_t stream) {
    const float* raw = (const float*)d_in[0];
    char* ws = (char*)d_ws;
    float* sx1 = (float*)(ws + 0);
    float* sy1 = (float*)(ws + 16384);
    float* sx2 = (float*)(ws + 32768);
    float* sy2 = (float*)(ws + 49152);
    float* sconf = (float*)(ws + 65536);
    int* Mp = (int*)(ws + 81920);
    u64* diagR  = (u64*)(ws + 86016);
    u64* carry1 = (u64*)(ws + 118784);
    u64* carry2 = (u64*)(ws + 151552);
    u64* carry3 = (u64*)(ws + 184320);
    u64* maskT  = (u64*)(ws + 262144);
    int* rank_partial = (int*)(ws + 2359296);
    float* out = (float*)d_out;

    k_rank<<<dim3(16, 16), dim3(256), 0, stream>>>(raw, rank_partial, Mp);
    k_scatter<<<dim3(16), dim3(256), 0, stream>>>(raw, rank_partial, sx1, sy1, sx2, sy2, sconf, Mp);
    k_mask<<<dim3(16, 64), dim3(256), 0, stream>>>(sx1, sy1, sx2, sy2, Mp, maskT, diagR, carry1, carry2, carry3);
    k_scan<<<dim3(1), dim3(576), 0, stream>>>(Mp, maskT, diagR, carry1, carry2, carry3, sx1, sy1, sx2, sy2, sconf, out);
}